// Round 24
// baseline (22.346 us; speedup 1.0000x reference)
//
#include <hip/hip_runtime.h>
#include <math.h>

#define BATCH 32
#define H 512
#define W 512
#define PAD 15
#define BAND 8                        /* rows per block */
#define NBANDS (H / BAND)             /* 64 */
#define NBLOCKS (BATCH * NBANDS)      /* 2048 */
#define NTHREADS 512                  /* 8 waves: 1 row/wave, 1 col/thread */
#define NPART (NBLOCKS * 8)           /* 16384 wave partials */
#define NXCD 8
#define INV_KK (1.0f / 961.0f)

/* ---------- fused weight + stable BCE for one element (verified R8) ------ */
#define EMIT(tv, lv, hs)                                                      \
    {                                                                         \
        float pooled_ = (hs) * INV_KK;                                        \
        float wgt_ = fmaf(5.f, fabsf(pooled_ - (tv)), 1.f);                   \
        float al_ = fabsf(lv);                                                \
        float bce_ = fmaxf((lv), 0.f) - (lv) * (tv)                           \
                     + __logf(1.f + __expf(-al_));                            \
        num = fmaf(wgt_, bce_, num);                                          \
        den += wgt_;                                                          \
    }

/* one k-slot of the horizontal 31-window (verified bit-exact R7..R23) */
#define KSLOT(pk, pkm1, tv, lv, FIRST, LAST)                                  \
    {                                                                         \
        float hs_ = base_;                                                    \
        if (!(LAST)) {                                                        \
            float sa_ = __shfl_up(tot_ - (pk), 2);                            \
            hs_ += okm2 ? sa_ : 0.f;                                          \
        }                                                                     \
        if (!(FIRST)) {                                                       \
            float se_ = __shfl_down((pkm1), 2);                               \
            hs_ += okp2 ? se_ : 0.f;                                          \
        }                                                                     \
        EMIT(tv, lv, hs_)                                                     \
    }

/* full row: logits from registers (prefetched pre-barrier), t from traw,
   vs from LDS. Phase 2 has ZERO global loads. */
#define ROWPASS(r, La_, Lb_)                                                  \
    {                                                                         \
        float4 A_  = ((const float4*)vs[(r)])[2 * lane];                      \
        float4 B_  = ((const float4*)vs[(r)])[2 * lane + 1];                  \
        float4 Ta_ = ((const float4*)traw[(r)])[2 * lane];                    \
        float4 Tb_ = ((const float4*)traw[(r)])[2 * lane + 1];                \
        const float p0_ = A_.x;                                               \
        const float p1_ = p0_ + A_.y;                                         \
        const float p2_ = p1_ + A_.z;                                         \
        const float p3_ = p2_ + A_.w;                                         \
        const float p4_ = p3_ + B_.x;                                         \
        const float p5_ = p4_ + B_.y;                                         \
        const float p6_ = p5_ + B_.z;                                         \
        const float tot_ = p6_ + B_.w;                                        \
        const float bm_ = __shfl_up(tot_, 1);                                 \
        const float dp_ = __shfl_down(tot_, 1);                               \
        const float base_ = (okm1 ? bm_ : 0.f) + tot_ + (okp1 ? dp_ : 0.f);   \
        KSLOT(p0_, 0.f, Ta_.x, La_.x, 1, 0)                                   \
        KSLOT(p1_, p0_, Ta_.y, La_.y, 0, 0)                                   \
        KSLOT(p2_, p1_, Ta_.z, La_.z, 0, 0)                                   \
        KSLOT(p3_, p2_, Ta_.w, La_.w, 0, 0)                                   \
        KSLOT(p4_, p3_, Tb_.x, Lb_.x, 0, 0)                                   \
        KSLOT(p5_, p4_, Tb_.y, Lb_.y, 0, 0)                                   \
        KSLOT(p6_, p5_, Tb_.z, Lb_.z, 0, 0)                                   \
        KSLOT(0.f, p6_, Tb_.w, Lb_.w, 0, 1)                                   \
    }

/* ---------- Phase 1: PIPELINED vertical running windows into LDS -------- */
/* thread owns ONE column (tid). Register double-buffer: chunk k+1's loads
   issue before chunk k's consume (explicit textual order — R16/R17 taught
   us the scheduler must be forced). All array indices compile-time.        */
#define LOADC(G, arr, C0, N)                                                  \
    _Pragma("unroll")                                                         \
    for (int i = 0; i < (N); ++i) {                                           \
        const int y = y0 + (C0) + i - PAD;                                    \
        arr[i] = 0.f;                                                         \
        if ((G) || (unsigned)y < (unsigned)H) arr[i] = tcol[y * W];           \
    }

/* consume: accumulate + stash band rows (c in [15, 15+BAND)) to traw */
#define CONSUME(arr, C0, N)                                                   \
    _Pragma("unroll")                                                         \
    for (int i = 0; i < (N); ++i) {                                           \
        const int c = (C0) + i;                                               \
        run0 += arr[i];                                                       \
        if (c >= PAD && c < PAD + BAND) traw[c - PAD][tid] = arr[i];          \
    }

#define PHASE1(G)                                                             \
    {                                                                         \
        float pA[8], pB[8];                                                   \
        LOADC(G, pA, 0, 8)                                                    \
        LOADC(G, pB, 8, 8)                                                    \
        __builtin_amdgcn_sched_barrier(0);                                    \
        CONSUME(pA, 0, 8)                                                     \
        LOADC(G, pA, 16, 8)                                                   \
        __builtin_amdgcn_sched_barrier(0);                                    \
        CONSUME(pB, 8, 8)                                                     \
        LOADC(G, pB, 24, 7)                                                   \
        __builtin_amdgcn_sched_barrier(0);                                    \
        CONSUME(pA, 16, 8)                                                    \
        /* slide rows: enter e[j]=row y0+16+j, leave s[j]=row y0-15+j */      \
        float se[7], ss[7];                                                   \
        _Pragma("unroll")                                                     \
        for (int j = 0; j < 7; ++j) {                                         \
            const int ye = y0 + PAD + 1 + j, yl = y0 - PAD + j;               \
            se[j] = 0.f; ss[j] = 0.f;                                         \
            if ((G) || (unsigned)ye < (unsigned)H) se[j] = tcol[ye * W];      \
            if ((G) || (unsigned)yl < (unsigned)H) ss[j] = tcol[yl * W];      \
        }                                                                     \
        __builtin_amdgcn_sched_barrier(0);                                    \
        CONSUME(pB, 24, 7)                                                    \
        /* slide: pure ALU + LDS writes, no loads on the chain */             \
        _Pragma("unroll")                                                     \
        for (int j = 0; j < BAND; ++j) {                                      \
            vs[j][tid] = run0;                                                \
            if (j < BAND - 1) run0 += se[j] - ss[j];                          \
        }                                                                     \
    }

__global__ __launch_bounds__(NTHREADS)
void wbce_band_kernel(const float* __restrict__ logits,
                      const float* __restrict__ targets,
                      float2* __restrict__ partials) {
    __shared__ __align__(16) float vs[BAND][W];     /* 16 KB */
    __shared__ __align__(16) float traw[BAND][W];   /* 16 KB */

    const int tid  = threadIdx.x;
    const int lane = tid & 63;
    const int w    = tid >> 6;                    /* wave id 0..7 = row */

    /* XCD-aware bijective swizzle: 256 consecutive blocks (4 images) per XCD */
    const int bid  = (int)blockIdx.x;
    const int sbid = (bid & (NXCD - 1)) * (NBLOCKS / NXCD) + (bid >> 3);

    const int img  = sbid >> 6;            /* sbid / NBANDS */
    const int band = sbid & (NBANDS - 1);
    const int y0   = band * BAND;
    const int x0   = lane * 8;

    const float* tb = targets + (size_t)img * H * W;
    const float* lb = logits  + (size_t)img * H * W;
    const float* tcol = tb + tid;

    /* ---- Phase 1: cooperative vertical 31-row windows -> LDS ---- */
    float run0 = 0.f;
    if (y0 >= PAD && y0 + BAND + PAD - 1 < H) {
        PHASE1(1)
    } else {
        PHASE1(0)
    }

    /* ---- logits prefetch: issued post-slide, latency hidden under the
       barrier wait + Phase 2's LDS reads (carry = 8 VGPR across barrier) ---- */
    __builtin_amdgcn_sched_barrier(0);
    const float4* lp_ = (const float4*)(lb + (size_t)(y0 + w) * W + x0);
    float4 Lpa = lp_[0], Lpb = lp_[1];
    __builtin_amdgcn_sched_barrier(0);
    __syncthreads();

    /* ---- Phase 2: horizontal window + fused weight/BCE (wave = 1 row) ---- */
    const bool okm2 = lane >= 2, okm1 = lane >= 1;
    const bool okp1 = lane <= 62, okp2 = lane <= 61;
    float num = 0.f, den = 0.f;

    ROWPASS(w, Lpa, Lpb)

    /* ---- wave reduction, one partial pair per wave ---- */
    #pragma unroll
    for (int off = 32; off > 0; off >>= 1) {
        num += __shfl_down(num, off);
        den += __shfl_down(den, off);
    }
    if (lane == 0) {
        partials[sbid * 8 + w] = make_float2(num, den);
    }
}

/* 16384 partial pairs -> scalar. Image i owns pairs [i*512, i*512+512). */
__global__ __launch_bounds__(1024)
void wbce_finalize_kernel(const float2* __restrict__ partials,
                          float* __restrict__ out) {
    __shared__ float rsum[16];
    const int t = threadIdx.x;
    const int img = t >> 5;
    const int j = t & 31;
    const int base = img * 512;
    float num = 0.f, den = 0.f;
    #pragma unroll
    for (int k = 0; k < 16; ++k) {
        float2 p = partials[base + j + 32 * k];
        num += p.x; den += p.y;
    }
    #pragma unroll
    for (int off = 16; off > 0; off >>= 1) {
        num += __shfl_down(num, off, 32);
        den += __shfl_down(den, off, 32);
    }
    float ratio = 0.f;
    if ((t & 31) == 0) ratio = num / den;
    ratio += __shfl_down(ratio, 32);          /* lane0 += lane32 */
    const int lane = t & 63;
    const int wv = t >> 6;
    if (lane == 0) rsum[wv] = ratio;
    __syncthreads();
    if (t == 0) {
        float s = 0.f;
        #pragma unroll
        for (int i = 0; i < 16; ++i) s += rsum[i];
        out[0] = s / (float)BATCH;
    }
}

extern "C" void kernel_launch(void* const* d_in, const int* in_sizes, int n_in,
                              void* d_out, int out_size, void* d_ws, size_t ws_size,
                              hipStream_t stream) {
    const float* logits  = (const float*)d_in[0];
    const float* targets = (const float*)d_in[1];
    float* out = (float*)d_out;
    float2* partials = (float2*)d_ws;   /* NPART float2 = 128 KB */

    wbce_band_kernel<<<NBLOCKS, NTHREADS, 0, stream>>>(logits, targets, partials);
    wbce_finalize_kernel<<<1, 1024, 0, stream>>>(partials, out);
}

// Round 25
// 21.786 us; speedup vs baseline: 1.0257x; 1.0257x over previous
//
#include <hip/hip_runtime.h>
#include <math.h>

#define BATCH 32
#define H 512
#define W 512
#define PAD 15
#define BAND 8                        /* rows per block */
#define NBANDS (H / BAND)             /* 64 */
#define NBLOCKS (BATCH * NBANDS)      /* 2048 */
#define NTHREADS 512                  /* 8 waves: 1 row/wave, 1 col/thread */
#define NPART (NBLOCKS * 8)           /* 16384 wave partials */
#define NXCD 8
#define INV_KK (1.0f / 961.0f)

/* ---------- fused weight + stable BCE for one element (verified R8) ------ */
#define EMIT(tv, lv, hs)                                                      \
    {                                                                         \
        float pooled_ = (hs) * INV_KK;                                        \
        float wgt_ = fmaf(5.f, fabsf(pooled_ - (tv)), 1.f);                   \
        float al_ = fabsf(lv);                                                \
        float bce_ = fmaxf((lv), 0.f) - (lv) * (tv)                           \
                     + __logf(1.f + __expf(-al_));                            \
        num = fmaf(wgt_, bce_, num);                                          \
        den += wgt_;                                                          \
    }

/* one k-slot of the horizontal 31-window (verified bit-exact R7..R24) */
#define KSLOT(pk, pkm1, tv, lv, FIRST, LAST)                                  \
    {                                                                         \
        float hs_ = base_;                                                    \
        if (!(LAST)) {                                                        \
            float sa_ = __shfl_up(tot_ - (pk), 2);                            \
            hs_ += okm2 ? sa_ : 0.f;                                          \
        }                                                                     \
        if (!(FIRST)) {                                                       \
            float se_ = __shfl_down((pkm1), 2);                               \
            hs_ += okp2 ? se_ : 0.f;                                          \
        }                                                                     \
        EMIT(tv, lv, hs_)                                                     \
    }

/* full row: logits global load issued FIRST (longest latency), then LDS
   vertical sums + stashed raw t; horizontal window + BCE. (R23 champion) */
#define ROWPASS(r)                                                            \
    {                                                                         \
        const float4* lp_ = (const float4*)(lb + (size_t)(y0 + (r)) * W + x0);\
        float4 La_ = lp_[0], Lb_ = lp_[1];                                    \
        float4 A_  = ((const float4*)vs[(r)])[2 * lane];                      \
        float4 B_  = ((const float4*)vs[(r)])[2 * lane + 1];                  \
        float4 Ta_ = ((const float4*)traw[(r)])[2 * lane];                    \
        float4 Tb_ = ((const float4*)traw[(r)])[2 * lane + 1];                \
        const float p0_ = A_.x;                                               \
        const float p1_ = p0_ + A_.y;                                         \
        const float p2_ = p1_ + A_.z;                                         \
        const float p3_ = p2_ + A_.w;                                         \
        const float p4_ = p3_ + B_.x;                                         \
        const float p5_ = p4_ + B_.y;                                         \
        const float p6_ = p5_ + B_.z;                                         \
        const float tot_ = p6_ + B_.w;                                        \
        const float bm_ = __shfl_up(tot_, 1);                                 \
        const float dp_ = __shfl_down(tot_, 1);                               \
        const float base_ = (okm1 ? bm_ : 0.f) + tot_ + (okp1 ? dp_ : 0.f);   \
        KSLOT(p0_, 0.f, Ta_.x, La_.x, 1, 0)                                   \
        KSLOT(p1_, p0_, Ta_.y, La_.y, 0, 0)                                   \
        KSLOT(p2_, p1_, Ta_.z, La_.z, 0, 0)                                   \
        KSLOT(p3_, p2_, Ta_.w, La_.w, 0, 0)                                   \
        KSLOT(p4_, p3_, Tb_.x, Lb_.x, 0, 0)                                   \
        KSLOT(p5_, p4_, Tb_.y, Lb_.y, 0, 0)                                   \
        KSLOT(p6_, p5_, Tb_.z, Lb_.z, 0, 0)                                   \
        KSLOT(0.f, p6_, Tb_.w, Lb_.w, 0, 1)                                   \
    }

/* ---------- Phase 1: PIPELINED vertical running windows into LDS -------- */
/* thread owns ONE column (tid). Register double-buffer: chunk k+1's loads
   issue before chunk k's consume (explicit textual order — R16/R17 taught
   us the scheduler must be forced). All array indices compile-time.
   R25: se/ss slide-row batch hoisted one stage earlier so TWO consume
   stages cover its latency instead of one.                                 */
#define LOADC(G, arr, C0, N)                                                  \
    _Pragma("unroll")                                                         \
    for (int i = 0; i < (N); ++i) {                                           \
        const int y = y0 + (C0) + i - PAD;                                    \
        arr[i] = 0.f;                                                         \
        if ((G) || (unsigned)y < (unsigned)H) arr[i] = tcol[y * W];           \
    }

/* consume: accumulate + stash band rows (c in [15, 15+BAND)) to traw */
#define CONSUME(arr, C0, N)                                                   \
    _Pragma("unroll")                                                         \
    for (int i = 0; i < (N); ++i) {                                           \
        const int c = (C0) + i;                                               \
        run0 += arr[i];                                                       \
        if (c >= PAD && c < PAD + BAND) traw[c - PAD][tid] = arr[i];          \
    }

#define PHASE1(G)                                                             \
    {                                                                         \
        float pA[8], pB[8];                                                   \
        LOADC(G, pA, 0, 8)                                                    \
        LOADC(G, pB, 8, 8)                                                    \
        __builtin_amdgcn_sched_barrier(0);                                    \
        CONSUME(pA, 0, 8)                                                     \
        LOADC(G, pA, 16, 8)                                                   \
        __builtin_amdgcn_sched_barrier(0);                                    \
        CONSUME(pB, 8, 8)                                                     \
        LOADC(G, pB, 24, 7)                                                   \
        /* slide rows issued HERE (hoisted): enter e[j]=row y0+16+j,          \
           leave s[j]=row y0-15+j; covered by the next TWO consumes */        \
        float se[7], ss[7];                                                   \
        _Pragma("unroll")                                                     \
        for (int j = 0; j < 7; ++j) {                                         \
            const int ye = y0 + PAD + 1 + j, yl = y0 - PAD + j;               \
            se[j] = 0.f; ss[j] = 0.f;                                         \
            if ((G) || (unsigned)ye < (unsigned)H) se[j] = tcol[ye * W];      \
            if ((G) || (unsigned)yl < (unsigned)H) ss[j] = tcol[yl * W];      \
        }                                                                     \
        __builtin_amdgcn_sched_barrier(0);                                    \
        CONSUME(pA, 16, 8)                                                    \
        __builtin_amdgcn_sched_barrier(0);                                    \
        CONSUME(pB, 24, 7)                                                    \
        /* slide: pure ALU + LDS writes, no loads on the chain */             \
        _Pragma("unroll")                                                     \
        for (int j = 0; j < BAND; ++j) {                                      \
            vs[j][tid] = run0;                                                \
            if (j < BAND - 1) run0 += se[j] - ss[j];                          \
        }                                                                     \
    }

__global__ __launch_bounds__(NTHREADS)
void wbce_band_kernel(const float* __restrict__ logits,
                      const float* __restrict__ targets,
                      float2* __restrict__ partials) {
    __shared__ __align__(16) float vs[BAND][W];     /* 16 KB */
    __shared__ __align__(16) float traw[BAND][W];   /* 16 KB */

    const int tid  = threadIdx.x;
    const int lane = tid & 63;
    const int w    = tid >> 6;                    /* wave id 0..7 = row */

    /* XCD-aware bijective swizzle: 256 consecutive blocks (4 images) per XCD */
    const int bid  = (int)blockIdx.x;
    const int sbid = (bid & (NXCD - 1)) * (NBLOCKS / NXCD) + (bid >> 3);

    const int img  = sbid >> 6;            /* sbid / NBANDS */
    const int band = sbid & (NBANDS - 1);
    const int y0   = band * BAND;
    const int x0   = lane * 8;

    const float* tb = targets + (size_t)img * H * W;
    const float* lb = logits  + (size_t)img * H * W;
    const float* tcol = tb + tid;

    /* ---- Phase 1: cooperative vertical 31-row windows -> LDS ---- */
    float run0 = 0.f;
    if (y0 >= PAD && y0 + BAND + PAD - 1 < H) {
        PHASE1(1)
    } else {
        PHASE1(0)
    }
    __syncthreads();

    /* ---- Phase 2: horizontal window + fused weight/BCE (wave = 1 row) ---- */
    const bool okm2 = lane >= 2, okm1 = lane >= 1;
    const bool okp1 = lane <= 62, okp2 = lane <= 61;
    float num = 0.f, den = 0.f;

    ROWPASS(w)

    /* ---- wave reduction, one partial pair per wave ---- */
    #pragma unroll
    for (int off = 32; off > 0; off >>= 1) {
        num += __shfl_down(num, off);
        den += __shfl_down(den, off);
    }
    if (lane == 0) {
        partials[sbid * 8 + w] = make_float2(num, den);
    }
}

/* 16384 partial pairs -> scalar. Image i owns pairs [i*512, i*512+512). */
__global__ __launch_bounds__(1024)
void wbce_finalize_kernel(const float2* __restrict__ partials,
                          float* __restrict__ out) {
    __shared__ float rsum[16];
    const int t = threadIdx.x;
    const int img = t >> 5;
    const int j = t & 31;
    const int base = img * 512;
    float num = 0.f, den = 0.f;
    #pragma unroll
    for (int k = 0; k < 16; ++k) {
        float2 p = partials[base + j + 32 * k];
        num += p.x; den += p.y;
    }
    #pragma unroll
    for (int off = 16; off > 0; off >>= 1) {
        num += __shfl_down(num, off, 32);
        den += __shfl_down(den, off, 32);
    }
    float ratio = 0.f;
    if ((t & 31) == 0) ratio = num / den;
    ratio += __shfl_down(ratio, 32);          /* lane0 += lane32 */
    const int lane = t & 63;
    const int wv = t >> 6;
    if (lane == 0) rsum[wv] = ratio;
    __syncthreads();
    if (t == 0) {
        float s = 0.f;
        #pragma unroll
        for (int i = 0; i < 16; ++i) s += rsum[i];
        out[0] = s / (float)BATCH;
    }
}

extern "C" void kernel_launch(void* const* d_in, const int* in_sizes, int n_in,
                              void* d_out, int out_size, void* d_ws, size_t ws_size,
                              hipStream_t stream) {
    const float* logits  = (const float*)d_in[0];
    const float* targets = (const float*)d_in[1];
    float* out = (float*)d_out;
    float2* partials = (float2*)d_ws;   /* NPART float2 = 128 KB */

    wbce_band_kernel<<<NBLOCKS, NTHREADS, 0, stream>>>(logits, targets, partials);
    wbce_finalize_kernel<<<1, 1024, 0, stream>>>(partials, out);
}

// Round 26
// 20.813 us; speedup vs baseline: 1.0736x; 1.0467x over previous
//
#include <hip/hip_runtime.h>
#include <math.h>

#define BATCH 32
#define H 512
#define W 512
#define PAD 15
#define BAND 8                        /* rows per block */
#define NBANDS (H / BAND)             /* 64 */
#define NBLOCKS (BATCH * NBANDS)      /* 2048 */
#define NTHREADS 512                  /* 8 waves: 1 row/wave, 1 col/thread */
#define NPART (NBLOCKS * 8)           /* 16384 wave partials */
#define NXCD 8
#define INV_KK (1.0f / 961.0f)

/* ---------- fused weight + stable BCE for one element (verified R8) ------ */
#define EMIT(tv, lv, hs)                                                      \
    {                                                                         \
        float pooled_ = (hs) * INV_KK;                                        \
        float wgt_ = fmaf(5.f, fabsf(pooled_ - (tv)), 1.f);                   \
        float al_ = fabsf(lv);                                                \
        float bce_ = fmaxf((lv), 0.f) - (lv) * (tv)                           \
                     + __logf(1.f + __expf(-al_));                            \
        num = fmaf(wgt_, bce_, num);                                          \
        den += wgt_;                                                          \
    }

/* one k-slot of the horizontal 31-window (verified bit-exact R7..R25) */
#define KSLOT(pk, pkm1, tv, lv, FIRST, LAST)                                  \
    {                                                                         \
        float hs_ = base_;                                                    \
        if (!(LAST)) {                                                        \
            float sa_ = __shfl_up(tot_ - (pk), 2);                            \
            hs_ += okm2 ? sa_ : 0.f;                                          \
        }                                                                     \
        if (!(FIRST)) {                                                       \
            float se_ = __shfl_down((pkm1), 2);                               \
            hs_ += okp2 ? se_ : 0.f;                                          \
        }                                                                     \
        EMIT(tv, lv, hs_)                                                     \
    }

/* full row: logits global load issued FIRST (longest latency), then LDS
   vertical sums + stashed raw t; horizontal window + BCE. (R23 champion) */
#define ROWPASS(r)                                                            \
    {                                                                         \
        const float4* lp_ = (const float4*)(lb + (size_t)(y0 + (r)) * W + x0);\
        float4 La_ = lp_[0], Lb_ = lp_[1];                                    \
        float4 A_  = ((const float4*)vs[(r)])[2 * lane];                      \
        float4 B_  = ((const float4*)vs[(r)])[2 * lane + 1];                  \
        float4 Ta_ = ((const float4*)traw[(r)])[2 * lane];                    \
        float4 Tb_ = ((const float4*)traw[(r)])[2 * lane + 1];                \
        const float p0_ = A_.x;                                               \
        const float p1_ = p0_ + A_.y;                                         \
        const float p2_ = p1_ + A_.z;                                         \
        const float p3_ = p2_ + A_.w;                                         \
        const float p4_ = p3_ + B_.x;                                         \
        const float p5_ = p4_ + B_.y;                                         \
        const float p6_ = p5_ + B_.z;                                         \
        const float tot_ = p6_ + B_.w;                                        \
        const float bm_ = __shfl_up(tot_, 1);                                 \
        const float dp_ = __shfl_down(tot_, 1);                               \
        const float base_ = (okm1 ? bm_ : 0.f) + tot_ + (okp1 ? dp_ : 0.f);   \
        KSLOT(p0_, 0.f, Ta_.x, La_.x, 1, 0)                                   \
        KSLOT(p1_, p0_, Ta_.y, La_.y, 0, 0)                                   \
        KSLOT(p2_, p1_, Ta_.z, La_.z, 0, 0)                                   \
        KSLOT(p3_, p2_, Ta_.w, La_.w, 0, 0)                                   \
        KSLOT(p4_, p3_, Tb_.x, Lb_.x, 0, 0)                                   \
        KSLOT(p5_, p4_, Tb_.y, Lb_.y, 0, 0)                                   \
        KSLOT(p6_, p5_, Tb_.z, Lb_.z, 0, 0)                                   \
        KSLOT(0.f, p6_, Tb_.w, Lb_.w, 0, 1)                                   \
    }

/* ---------- Phase 1: 3-DEEP PIPELINED vertical windows into LDS --------- */
/* thread owns ONE column (tid). 24 init loads issued up front (single cold
   wait); remaining issue overlapped so every consume has >=2 stages of
   cover. Explicit textual order (R16/R17: scheduler must be forced).       */
#define LOADC(G, arr, C0, N)                                                  \
    _Pragma("unroll")                                                         \
    for (int i = 0; i < (N); ++i) {                                           \
        const int y = y0 + (C0) + i - PAD;                                    \
        arr[i] = 0.f;                                                         \
        if ((G) || (unsigned)y < (unsigned)H) arr[i] = tcol[y * W];           \
    }

/* consume: accumulate + stash band rows (c in [15, 15+BAND)) to traw */
#define CONSUME(arr, C0, N)                                                   \
    _Pragma("unroll")                                                         \
    for (int i = 0; i < (N); ++i) {                                           \
        const int c = (C0) + i;                                               \
        run0 += arr[i];                                                       \
        if (c >= PAD && c < PAD + BAND) traw[c - PAD][tid] = arr[i];          \
    }

#define PHASE1(G)                                                             \
    {                                                                         \
        float pA[8], pB[8], pC[8], pD[7];                                     \
        LOADC(G, pA, 0, 8)                                                    \
        LOADC(G, pB, 8, 8)                                                    \
        LOADC(G, pC, 16, 8)                                                   \
        __builtin_amdgcn_sched_barrier(0);                                    \
        CONSUME(pA, 0, 8)                                                     \
        LOADC(G, pD, 24, 7)                                                   \
        /* slide rows: enter se[j]=row y0+16+j, leave ss[j]=row y0-15+j */    \
        float se[7], ss[7];                                                   \
        _Pragma("unroll")                                                     \
        for (int j = 0; j < 7; ++j) {                                         \
            const int ye = y0 + PAD + 1 + j, yl = y0 - PAD + j;               \
            se[j] = 0.f; ss[j] = 0.f;                                         \
            if ((G) || (unsigned)ye < (unsigned)H) se[j] = tcol[ye * W];      \
            if ((G) || (unsigned)yl < (unsigned)H) ss[j] = tcol[yl * W];      \
        }                                                                     \
        __builtin_amdgcn_sched_barrier(0);                                    \
        CONSUME(pB, 8, 8)                                                     \
        __builtin_amdgcn_sched_barrier(0);                                    \
        CONSUME(pC, 16, 8)                                                    \
        __builtin_amdgcn_sched_barrier(0);                                    \
        CONSUME(pD, 24, 7)                                                    \
        /* slide: pure ALU + LDS writes, no loads on the chain */             \
        _Pragma("unroll")                                                     \
        for (int j = 0; j < BAND; ++j) {                                      \
            vs[j][tid] = run0;                                                \
            if (j < BAND - 1) run0 += se[j] - ss[j];                          \
        }                                                                     \
    }

__global__ __launch_bounds__(NTHREADS)
void wbce_band_kernel(const float* __restrict__ logits,
                      const float* __restrict__ targets,
                      float2* __restrict__ partials) {
    __shared__ __align__(16) float vs[BAND][W];     /* 16 KB */
    __shared__ __align__(16) float traw[BAND][W];   /* 16 KB */

    const int tid  = threadIdx.x;
    const int lane = tid & 63;
    const int w    = tid >> 6;                    /* wave id 0..7 = row */

    /* XCD-aware bijective swizzle: 256 consecutive blocks (4 images) per XCD */
    const int bid  = (int)blockIdx.x;
    const int sbid = (bid & (NXCD - 1)) * (NBLOCKS / NXCD) + (bid >> 3);

    const int img  = sbid >> 6;            /* sbid / NBANDS */
    const int band = sbid & (NBANDS - 1);
    const int y0   = band * BAND;
    const int x0   = lane * 8;

    const float* tb = targets + (size_t)img * H * W;
    const float* lb = logits  + (size_t)img * H * W;
    const float* tcol = tb + tid;

    /* ---- Phase 1: cooperative vertical 31-row windows -> LDS ---- */
    float run0 = 0.f;
    if (y0 >= PAD && y0 + BAND + PAD - 1 < H) {
        PHASE1(1)
    } else {
        PHASE1(0)
    }
    __syncthreads();

    /* ---- Phase 2: horizontal window + fused weight/BCE (wave = 1 row) ---- */
    const bool okm2 = lane >= 2, okm1 = lane >= 1;
    const bool okp1 = lane <= 62, okp2 = lane <= 61;
    float num = 0.f, den = 0.f;

    ROWPASS(w)

    /* ---- wave reduction, one partial pair per wave ---- */
    #pragma unroll
    for (int off = 32; off > 0; off >>= 1) {
        num += __shfl_down(num, off);
        den += __shfl_down(den, off);
    }
    if (lane == 0) {
        partials[sbid * 8 + w] = make_float2(num, den);
    }
}

/* 16384 partial pairs -> scalar, read as float4 (2 pairs/load).
   Image i owns pairs [i*512, i*512+512) = float4s [i*256, i*256+256). */
__global__ __launch_bounds__(1024)
void wbce_finalize_kernel(const float2* __restrict__ partials,
                          float* __restrict__ out) {
    __shared__ float rsum[16];
    const float4* p4 = (const float4*)partials;
    const int t = threadIdx.x;
    const int img = t >> 5;
    const int j = t & 31;
    const int base = img * 256;
    float num = 0.f, den = 0.f;
    #pragma unroll
    for (int k = 0; k < 8; ++k) {
        float4 p = p4[base + j + 32 * k];
        num += p.x + p.z;
        den += p.y + p.w;
    }
    #pragma unroll
    for (int off = 16; off > 0; off >>= 1) {
        num += __shfl_down(num, off, 32);
        den += __shfl_down(den, off, 32);
    }
    float ratio = 0.f;
    if ((t & 31) == 0) ratio = num / den;
    ratio += __shfl_down(ratio, 32);          /* lane0 += lane32 */
    const int lane = t & 63;
    const int wv = t >> 6;
    if (lane == 0) rsum[wv] = ratio;
    __syncthreads();
    if (t == 0) {
        float s = 0.f;
        #pragma unroll
        for (int i = 0; i < 16; ++i) s += rsum[i];
        out[0] = s / (float)BATCH;
    }
}

extern "C" void kernel_launch(void* const* d_in, const int* in_sizes, int n_in,
                              void* d_out, int out_size, void* d_ws, size_t ws_size,
                              hipStream_t stream) {
    const float* logits  = (const float*)d_in[0];
    const float* targets = (const float*)d_in[1];
    float* out = (float*)d_out;
    float2* partials = (float2*)d_ws;   /* NPART float2 = 128 KB */

    wbce_band_kernel<<<NBLOCKS, NTHREADS, 0, stream>>>(logits, targets, partials);
    wbce_finalize_kernel<<<1, 1024, 0, stream>>>(partials, out);
}

// Round 27
// 20.762 us; speedup vs baseline: 1.0763x; 1.0025x over previous
//
#include <hip/hip_runtime.h>
#include <math.h>

#define BATCH 32
#define H 512
#define W 512
#define PAD 15
#define BAND 8                        /* rows per block */
#define NBANDS (H / BAND)             /* 64 */
#define NBLOCKS (BATCH * NBANDS)      /* 2048 */
#define NTHREADS 512                  /* 8 waves: 1 row/wave, 1 col/thread */
#define NPART (NBLOCKS * 8)           /* 16384 wave partials */
#define NXCD 8
#define INV_KK (1.0f / 961.0f)

/* ---------- fused weight + stable BCE for one element (verified R8) ------ */
#define EMIT(tv, lv, hs)                                                      \
    {                                                                         \
        float pooled_ = (hs) * INV_KK;                                        \
        float wgt_ = fmaf(5.f, fabsf(pooled_ - (tv)), 1.f);                   \
        float al_ = fabsf(lv);                                                \
        float bce_ = fmaxf((lv), 0.f) - (lv) * (tv)                           \
                     + __logf(1.f + __expf(-al_));                            \
        num = fmaf(wgt_, bce_, num);                                          \
        den += wgt_;                                                          \
    }

/* one k-slot of the horizontal 31-window (verified bit-exact R7..R26) */
#define KSLOT(pk, pkm1, tv, lv, FIRST, LAST)                                  \
    {                                                                         \
        float hs_ = base_;                                                    \
        if (!(LAST)) {                                                        \
            float sa_ = __shfl_up(tot_ - (pk), 2);                            \
            hs_ += okm2 ? sa_ : 0.f;                                          \
        }                                                                     \
        if (!(FIRST)) {                                                       \
            float se_ = __shfl_down((pkm1), 2);                               \
            hs_ += okp2 ? se_ : 0.f;                                          \
        }                                                                     \
        EMIT(tv, lv, hs_)                                                     \
    }

/* full row: logits global load issued FIRST (longest latency), then LDS
   vertical sums + stashed raw t; horizontal window + BCE. (R23 champion) */
#define ROWPASS(r)                                                            \
    {                                                                         \
        const float4* lp_ = (const float4*)(lb + (size_t)(y0 + (r)) * W + x0);\
        float4 La_ = lp_[0], Lb_ = lp_[1];                                    \
        float4 A_  = ((const float4*)vs[(r)])[2 * lane];                      \
        float4 B_  = ((const float4*)vs[(r)])[2 * lane + 1];                  \
        float4 Ta_ = ((const float4*)traw[(r)])[2 * lane];                    \
        float4 Tb_ = ((const float4*)traw[(r)])[2 * lane + 1];                \
        const float p0_ = A_.x;                                               \
        const float p1_ = p0_ + A_.y;                                         \
        const float p2_ = p1_ + A_.z;                                         \
        const float p3_ = p2_ + A_.w;                                         \
        const float p4_ = p3_ + B_.x;                                         \
        const float p5_ = p4_ + B_.y;                                         \
        const float p6_ = p5_ + B_.z;                                         \
        const float tot_ = p6_ + B_.w;                                        \
        const float bm_ = __shfl_up(tot_, 1);                                 \
        const float dp_ = __shfl_down(tot_, 1);                               \
        const float base_ = (okm1 ? bm_ : 0.f) + tot_ + (okp1 ? dp_ : 0.f);   \
        KSLOT(p0_, 0.f, Ta_.x, La_.x, 1, 0)                                   \
        KSLOT(p1_, p0_, Ta_.y, La_.y, 0, 0)                                   \
        KSLOT(p2_, p1_, Ta_.z, La_.z, 0, 0)                                   \
        KSLOT(p3_, p2_, Ta_.w, La_.w, 0, 0)                                   \
        KSLOT(p4_, p3_, Tb_.x, Lb_.x, 0, 0)                                   \
        KSLOT(p5_, p4_, Tb_.y, Lb_.y, 0, 0)                                   \
        KSLOT(p6_, p5_, Tb_.z, Lb_.z, 0, 0)                                   \
        KSLOT(0.f, p6_, Tb_.w, Lb_.w, 0, 1)                                   \
    }

/* ---------- Phase 1: FULL-ISSUE pipelined vertical windows into LDS ----- */
/* thread owns ONE column (tid). ALL 45 loads (31 init + 14 slide) issued
   up front — one cold wait, every consume fully covered. Explicit textual
   order (R16/R17: scheduler must be forced). ~45 regs in flight.           */
#define LOADC(G, arr, C0, N)                                                  \
    _Pragma("unroll")                                                         \
    for (int i = 0; i < (N); ++i) {                                           \
        const int y = y0 + (C0) + i - PAD;                                    \
        arr[i] = 0.f;                                                         \
        if ((G) || (unsigned)y < (unsigned)H) arr[i] = tcol[y * W];           \
    }

/* consume: accumulate + stash band rows (c in [15, 15+BAND)) to traw */
#define CONSUME(arr, C0, N)                                                   \
    _Pragma("unroll")                                                         \
    for (int i = 0; i < (N); ++i) {                                           \
        const int c = (C0) + i;                                               \
        run0 += arr[i];                                                       \
        if (c >= PAD && c < PAD + BAND) traw[c - PAD][tid] = arr[i];          \
    }

#define PHASE1(G)                                                             \
    {                                                                         \
        float pA[8], pB[8], pC[8], pD[7];                                     \
        float se[7], ss[7];                                                   \
        LOADC(G, pA, 0, 8)                                                    \
        LOADC(G, pB, 8, 8)                                                    \
        LOADC(G, pC, 16, 8)                                                   \
        LOADC(G, pD, 24, 7)                                                   \
        /* slide rows: enter se[j]=row y0+16+j, leave ss[j]=row y0-15+j */    \
        _Pragma("unroll")                                                     \
        for (int j = 0; j < 7; ++j) {                                         \
            const int ye = y0 + PAD + 1 + j, yl = y0 - PAD + j;               \
            se[j] = 0.f; ss[j] = 0.f;                                         \
            if ((G) || (unsigned)ye < (unsigned)H) se[j] = tcol[ye * W];      \
            if ((G) || (unsigned)yl < (unsigned)H) ss[j] = tcol[yl * W];      \
        }                                                                     \
        __builtin_amdgcn_sched_barrier(0);                                    \
        CONSUME(pA, 0, 8)                                                     \
        __builtin_amdgcn_sched_barrier(0);                                    \
        CONSUME(pB, 8, 8)                                                     \
        __builtin_amdgcn_sched_barrier(0);                                    \
        CONSUME(pC, 16, 8)                                                    \
        __builtin_amdgcn_sched_barrier(0);                                    \
        CONSUME(pD, 24, 7)                                                    \
        /* slide: pure ALU + LDS writes, no loads on the chain */             \
        _Pragma("unroll")                                                     \
        for (int j = 0; j < BAND; ++j) {                                      \
            vs[j][tid] = run0;                                                \
            if (j < BAND - 1) run0 += se[j] - ss[j];                          \
        }                                                                     \
    }

__global__ __launch_bounds__(NTHREADS)
void wbce_band_kernel(const float* __restrict__ logits,
                      const float* __restrict__ targets,
                      float2* __restrict__ partials) {
    __shared__ __align__(16) float vs[BAND][W];     /* 16 KB */
    __shared__ __align__(16) float traw[BAND][W];   /* 16 KB */

    const int tid  = threadIdx.x;
    const int lane = tid & 63;
    const int w    = tid >> 6;                    /* wave id 0..7 = row */

    /* XCD-aware bijective swizzle: 256 consecutive blocks (4 images) per XCD */
    const int bid  = (int)blockIdx.x;
    const int sbid = (bid & (NXCD - 1)) * (NBLOCKS / NXCD) + (bid >> 3);

    const int img  = sbid >> 6;            /* sbid / NBANDS */
    const int band = sbid & (NBANDS - 1);
    const int y0   = band * BAND;
    const int x0   = lane * 8;

    const float* tb = targets + (size_t)img * H * W;
    const float* lb = logits  + (size_t)img * H * W;
    const float* tcol = tb + tid;

    /* ---- Phase 1: cooperative vertical 31-row windows -> LDS ---- */
    float run0 = 0.f;
    if (y0 >= PAD && y0 + BAND + PAD - 1 < H) {
        PHASE1(1)
    } else {
        PHASE1(0)
    }
    __syncthreads();

    /* ---- Phase 2: horizontal window + fused weight/BCE (wave = 1 row) ---- */
    const bool okm2 = lane >= 2, okm1 = lane >= 1;
    const bool okp1 = lane <= 62, okp2 = lane <= 61;
    float num = 0.f, den = 0.f;

    ROWPASS(w)

    /* ---- wave reduction, one partial pair per wave ---- */
    #pragma unroll
    for (int off = 32; off > 0; off >>= 1) {
        num += __shfl_down(num, off);
        den += __shfl_down(den, off);
    }
    if (lane == 0) {
        partials[sbid * 8 + w] = make_float2(num, den);
    }
}

/* 16384 partial pairs -> scalar, read as float4 (2 pairs/load).
   Image i owns pairs [i*512, i*512+512) = float4s [i*256, i*256+256). */
__global__ __launch_bounds__(1024)
void wbce_finalize_kernel(const float2* __restrict__ partials,
                          float* __restrict__ out) {
    __shared__ float rsum[16];
    const float4* p4 = (const float4*)partials;
    const int t = threadIdx.x;
    const int img = t >> 5;
    const int j = t & 31;
    const int base = img * 256;
    float num = 0.f, den = 0.f;
    #pragma unroll
    for (int k = 0; k < 8; ++k) {
        float4 p = p4[base + j + 32 * k];
        num += p.x + p.z;
        den += p.y + p.w;
    }
    #pragma unroll
    for (int off = 16; off > 0; off >>= 1) {
        num += __shfl_down(num, off, 32);
        den += __shfl_down(den, off, 32);
    }
    float ratio = 0.f;
    if ((t & 31) == 0) ratio = num / den;
    ratio += __shfl_down(ratio, 32);          /* lane0 += lane32 */
    const int lane = t & 63;
    const int wv = t >> 6;
    if (lane == 0) rsum[wv] = ratio;
    __syncthreads();
    if (t == 0) {
        float s = 0.f;
        #pragma unroll
        for (int i = 0; i < 16; ++i) s += rsum[i];
        out[0] = s / (float)BATCH;
    }
}

extern "C" void kernel_launch(void* const* d_in, const int* in_sizes, int n_in,
                              void* d_out, int out_size, void* d_ws, size_t ws_size,
                              hipStream_t stream) {
    const float* logits  = (const float*)d_in[0];
    const float* targets = (const float*)d_in[1];
    float* out = (float*)d_out;
    float2* partials = (float2*)d_ws;   /* NPART float2 = 128 KB */

    wbce_band_kernel<<<NBLOCKS, NTHREADS, 0, stream>>>(logits, targets, partials);
    wbce_finalize_kernel<<<1, 1024, 0, stream>>>(partials, out);
}